// Round 6
// baseline (229.071 us; speedup 1.0000x reference)
//
#include <hip/hip_runtime.h>
#include <stdint.h>

// Problem constants (fixed by setup_inputs).
#define N_LIDAR   8192
#define M_QUERIES 32768   // 1024 rays * 32 samples
#define D_FEAT    128
#define BLOCK     256
#define SEG       512                      // candidates per block (both phases)
#define NSEG      (N_LIDAR / SEG)          // 16
#define N_QBLK    (M_QUERIES / BLOCK)      // 128 query-blocks (256 queries each)

// Filter slack (one-sided approx error, doubled) — HW-proven in prior session.
#define EPS2 0.008f

typedef __attribute__((ext_vector_type(8)))  short bf16x8;
typedef __attribute__((ext_vector_type(16))) float f32x16;

// Workspace layout (~3.0 MB):
#define WS_KEYS  0                         // 32768 * 8   u64 exact argmin keys
#define WS_GPART 262144                    // 32768 * 16 * 4  per-stripe partial mins
#define WS_QPK   2359296                   // 32768 * 16  float4 (x,y,z,qs)
#define WS_CPK   2883584                   //  8192 * 16  float4 (-2lx,-2ly,-2lz,ks)
#define WS_CNT   3014656                   //   128 * 4   u32 per-qblock done counters

// Split f32 into bf16 hi + bf16 lo (RNE).
__device__ __forceinline__ void bsplit(float v, short& h, short& l) {
    unsigned u = __float_as_uint(v);
    unsigned r = (u + 0x7FFFu + ((u >> 16) & 1u)) & 0xFFFF0000u;
    h = (short)(r >> 16);
    float lo = v - __uint_as_float(r);
    unsigned u2 = __float_as_uint(lo);
    l = (short)((u2 + 0x7FFFu + ((u2 >> 16) & 1u)) >> 16);
}

#define BF_ONE ((short)0x3F80)

// Plain fminf tree over 16 regs (HW-verified bitwise in r8/r9 diagnostics).
__device__ __forceinline__ float vmin16_plain(const f32x16& v) {
    float a0 = fminf(v[0],  v[1]),  a1 = fminf(v[2],  v[3]);
    float a2 = fminf(v[4],  v[5]),  a3 = fminf(v[6],  v[7]);
    float a4 = fminf(v[8],  v[9]),  a5 = fminf(v[10], v[11]);
    float a6 = fminf(v[12], v[13]), a7 = fminf(v[14], v[15]);
    float b0 = fminf(a0, a1), b1 = fminf(a2, a3);
    float b2 = fminf(a4, a5), b3 = fminf(a6, a7);
    return fminf(fminf(b0, b1), fminf(b2, b3));
}

// Fragment builders — byte-identical to the proven prep_kernel encoding.
__device__ __forceinline__ void build_qrow(const float* __restrict__ pts, int q,
                                           short* dst, float4* qp_out) {
    #pragma clang fp contract(off)
    float x = pts[3 * q + 0], y = pts[3 * q + 1], z = pts[3 * q + 2];
    float qs = (x * x + y * y) + z * z;     // np rounding order, no FMA
    short xh, xl, yh, yl, zh, zl;
    bsplit(x, xh, xl); bsplit(y, yh, yl); bsplit(z, zh, zl);
    short a[16] = {xh, xh, xl, yh, yh, yl, zh, zh, zl,
                   BF_ONE, BF_ONE, 0, 0, 0, 0, 0};
    ((int4*)dst)[0] = *(const int4*)(a);
    ((int4*)dst)[1] = *(const int4*)(a + 8);
    if (qp_out) *qp_out = make_float4(x, y, z, qs);
}
__device__ __forceinline__ void build_crow(const float* __restrict__ lidar, int c,
                                           short* dst, float4* cp_out) {
    #pragma clang fp contract(off)
    float lx = lidar[3 * c + 0], ly = lidar[3 * c + 1], lz = lidar[3 * c + 2];
    float ks = (lx * lx + ly * ly) + lz * lz;   // np rounding order
    float Lx = -2.0f * lx, Ly = -2.0f * ly, Lz = -2.0f * lz;  // exact
    short xh, xl, yh, yl, zh, zl, kh, kl;
    bsplit(Lx, xh, xl); bsplit(Ly, yh, yl); bsplit(Lz, zh, zl); bsplit(ks, kh, kl);
    short b[16] = {xh, xl, xh, yh, yl, yh, zh, zl, zh,
                   kh, kl, 0, 0, 0, 0, 0};
    ((int4*)dst)[0] = *(const int4*)(b);
    ((int4*)dst)[1] = *(const int4*)(b + 8);
    if (cp_out) *cp_out = make_float4(Lx, Ly, Lz, ks);
}

// MFMA fragment addressing for v_mfma_f32_32x32x16_bf16 (HW-proven):
//   A[m][k]: m = lane&31, k = (lane>>5)*8 + j
//   B[k][n]: n = lane&31, k = (lane>>5)*8 + j
//   C/D    : col = lane&31, row = (reg&3) + 8*(reg>>2) + 4*(lane>>5)
// TRANSPOSED FORM (r8/r9 HW-verified bitwise): mfma(cand_frag, query_frag)
// -> D[row=candidate][col=query], per-pair bitwise equal.

// B-LDS rows use 48B slots (24 shorts): 32B fragment + 16B pad. ds_read_b128
// at stride 48 B -> max 4-way bank aliasing (vs 8-way at 32B stride).
#define BROW 24

// K1 = fused prep + p1. Grid (128 qblocks, 16 stripes). Builds fragments in
// LDS from raw inputs, per-lane min over stripe, direct-store partial min to
// gpart[q*16+stripe] (no atomics, no init). Side duties: qpack/keys/cnt
// (by==0), cpack (bx==0).
__global__ __launch_bounds__(BLOCK, 4)
void k1_kernel(const float* __restrict__ pts, const float* __restrict__ lidar,
               float* __restrict__ gpart, float4* __restrict__ qpack,
               float4* __restrict__ cpack, unsigned long long* __restrict__ keys,
               unsigned* __restrict__ cnt) {
    __shared__ short aL[256 * 16];
    __shared__ short bL[SEG * BROW];
    const int tid = threadIdx.x;
    const int bx = blockIdx.x, by = blockIdx.y;
    const int qb0 = bx * 256;
    const int segbase = by * SEG;

    {   // A rows: one query per thread (identical bytes to prep's Atab row)
        float4 qp;
        build_qrow(pts, qb0 + tid, aL + 16 * tid, &qp);
        if (by == 0) {
            qpack[qb0 + tid] = qp;
            keys[qb0 + tid]  = 0xFFFFFFFFFFFFFFFFull;
            if (tid == 0) cnt[bx] = 0u;
        }
    }
    #pragma unroll
    for (int j = tid; j < SEG; j += BLOCK) {   // B rows: 2 candidates/thread
        float4 cp;
        build_crow(lidar, segbase + j, bL + BROW * j, &cp);
        if (bx == 0) cpack[segbase + j] = cp;
    }
    __syncthreads();

    const int lane = tid & 63, wave = tid >> 6;
    const int half = lane >> 5, ln = lane & 31;
    const int qbase = qb0 + wave * 64;

    bf16x8 q0 = *(const bf16x8*)(aL + (wave * 64 + ln) * 16 + half * 8);
    bf16x8 q1 = *(const bf16x8*)(aL + (wave * 64 + 32 + ln) * 16 + half * 8);
    float m0 = __builtin_inff(), m1 = __builtin_inff();

    const short* cp = bL + ln * BROW + half * 8;
    #pragma unroll 2
    for (int g = 0; g < SEG / 32; ++g) {
        bf16x8 c = *(const bf16x8*)cp;
        cp += 32 * BROW;
        f32x16 z = 0.0f;
        f32x16 acc0 = __builtin_amdgcn_mfma_f32_32x32x16_bf16(c, q0, z, 0, 0, 0);
        f32x16 acc1 = __builtin_amdgcn_mfma_f32_32x32x16_bf16(c, q1, z, 0, 0, 0);
        m0 = fminf(m0, vmin16_plain(acc0));
        m1 = fminf(m1, vmin16_plain(acc1));
    }
    // Lanes ln / ln+32 hold the two half-sets of candidate rows of the same
    // query column -> one xor-32 merge completes the stripe min (r8-verified).
    m0 = fminf(m0, __shfl_xor(m0, 32));
    m1 = fminf(m1, __shfl_xor(m1, 32));

    if (half == 0) gpart[(qbase + ln) * NSEG + by]      = m0;
    else           gpart[(qbase + 32 + ln) * NSEG + by] = m1;
}

// Exact reference-rounded rescore of one (query, candidate) pair (proven).
__device__ __forceinline__ void rescore(int q, int c,
                                        const float4* __restrict__ qpack,
                                        const float4* __restrict__ cpack,
                                        unsigned long long* __restrict__ keys) {
    #pragma clang fp contract(off)
    float4 Q = qpack[q];
    float4 C = cpack[c];
    float cr = (Q.x * C.x + Q.y * C.y) + Q.z * C.z;  // = -2*cross, bit-exact
    float t  = Q.w + cr;                             // = fl(qs - 2*cross)
    float d2 = t + C.w;                              // = fl(t + ks)
    unsigned u = __float_as_uint(d2);
    u ^= (u >> 31) ? 0xFFFFFFFFu : 0x80000000u;
    unsigned long long key = ((unsigned long long)u << 13) | (unsigned)c;
    atomicMin(&keys[q], key);   // ties -> smaller index (np.argmin semantics)
}

// K2 = fused p2 + gather. Grid (128, 16). Threshold = min over the 16 gpart
// stripe-partials (bitwise same global min as the old atomicMin-gmin path).
// Main loop = r9-verified transposed p2 (LDS-sourced fragments). The last
// block of each qblock gathers the 256 queries' features.
//
// RACE FIX (r4 failed with absmax 5.19): the done-ticket MUST come after
// (a) __syncthreads — ALL warps of this block have issued their rescores
//     (tid 0's threadfence alone says nothing about sibling warps), then
// (b) __threadfence — those atomics are device-visible.
// Only then may tid 0 take its atomicAdd ticket. Standard last-block pattern.
__global__ __launch_bounds__(BLOCK, 4)
void k2_kernel(const float* __restrict__ pts, const float* __restrict__ lidar,
               const float* __restrict__ gpart,
               const float4* __restrict__ qpack, const float4* __restrict__ cpack,
               unsigned long long* __restrict__ keys, unsigned* __restrict__ cnt,
               const float4* __restrict__ feat, float4* __restrict__ out) {
    __shared__ short aL[256 * 16];
    __shared__ short bL[SEG * BROW];
    __shared__ int sidx[256];
    __shared__ int lastFlag;
    const int tid = threadIdx.x;
    const int bx = blockIdx.x, by = blockIdx.y;
    const int qb0 = bx * 256;
    const int segbase = by * SEG;

    build_qrow(pts, qb0 + tid, aL + 16 * tid, nullptr);
    #pragma unroll
    for (int j = tid; j < SEG; j += BLOCK)
        build_crow(lidar, segbase + j, bL + BROW * j, nullptr);
    __syncthreads();

    const int lane = tid & 63, wave = tid >> 6;
    const int half = lane >> 5, ln = lane & 31;
    const int qbase = qb0 + wave * 64;

    bf16x8 q0 = *(const bf16x8*)(aL + (wave * 64 + ln) * 16 + half * 8);
    bf16x8 q1 = *(const bf16x8*)(aL + (wave * 64 + 32 + ln) * 16 + half * 8);

    // Per-lane thresholds: min over 16 stripe partials (fminf of all stripe
    // mins == global min bitwise; partition-independent).
    float thr0, thr1;
    {
        const float4* g4 = (const float4*)(gpart + (qbase + ln) * NSEG);
        float4 u0 = g4[0], u1 = g4[1], u2 = g4[2], u3 = g4[3];
        float s0 = fminf(fminf(fminf(u0.x, u0.y), fminf(u0.z, u0.w)),
                         fminf(fminf(u1.x, u1.y), fminf(u1.z, u1.w)));
        float s1 = fminf(fminf(fminf(u2.x, u2.y), fminf(u2.z, u2.w)),
                         fminf(fminf(u3.x, u3.y), fminf(u3.z, u3.w)));
        thr0 = fminf(s0, s1) + EPS2;
        const float4* h4 = (const float4*)(gpart + (qbase + 32 + ln) * NSEG);
        float4 v0 = h4[0], v1 = h4[1], v2 = h4[2], v3 = h4[3];
        float t0 = fminf(fminf(fminf(v0.x, v0.y), fminf(v0.z, v0.w)),
                         fminf(fminf(v1.x, v1.y), fminf(v1.z, v1.w)));
        float t1 = fminf(fminf(fminf(v2.x, v2.y), fminf(v2.z, v2.w)),
                         fminf(fminf(v3.x, v3.y), fminf(v3.z, v3.w)));
        thr1 = fminf(t0, t1) + EPS2;
    }

    const short* cp = bL + ln * BROW + half * 8;
    for (int g = 0; g < SEG / 32; ++g) {
        bf16x8 c = *(const bf16x8*)cp;
        cp += 32 * BROW;
        f32x16 z = 0.0f;
        f32x16 acc0 = __builtin_amdgcn_mfma_f32_32x32x16_bf16(c, q0, z, 0, 0, 0);
        f32x16 acc1 = __builtin_amdgcn_mfma_f32_32x32x16_bf16(c, q1, z, 0, 0, 0);
        float t0 = vmin16_plain(acc0);
        float t1 = vmin16_plain(acc1);
        if (__any((t0 < thr0) | (t1 < thr1))) {
            const int cbase = segbase + g * 32 + 4 * half;
            unsigned mk0 = 0, mk1 = 0;
            #pragma unroll
            for (int r = 0; r < 16; ++r) mk0 = (acc0[r] < thr0) ? (mk0 | (1u << r)) : mk0;
            #pragma unroll
            for (int r = 0; r < 16; ++r) mk1 = (acc1[r] < thr1) ? (mk1 | (1u << r)) : mk1;
            while (mk0) {   // only hitting lanes iterate (exec-masked)
                int r = __builtin_ctz(mk0); mk0 &= mk0 - 1;
                rescore(qbase + ln, cbase + (r & 3) + 8 * (r >> 2),
                        qpack, cpack, keys);
            }
            while (mk1) {
                int r = __builtin_ctz(mk1); mk1 &= mk1 - 1;
                rescore(qbase + 32 + ln, cbase + (r & 3) + 8 * (r >> 2),
                        qpack, cpack, keys);
            }
        }
    }

    // --- fused gather: last block of this qblock finishes the 256 queries ---
    __syncthreads();       // (a) ALL warps of this block issued their rescores
    __threadfence();       // (b) those atomics are visible device-wide
    if (tid == 0) lastFlag = (atomicAdd(&cnt[bx], 1u) == (unsigned)(NSEG - 1));
    __syncthreads();
    if (lastFlag) {
        // Atomic RMW fetch of the final key (coherent at L2, no stale reads).
        unsigned long long k = atomicMin(&keys[qb0 + tid], 0xFFFFFFFFFFFFFFFFull);
        sidx[tid] = (int)(k & (unsigned long long)(N_LIDAR - 1));
        __syncthreads();
        const int l32 = tid & 31, grp = tid >> 5;   // 8 query-groups of 32 lanes
        #pragma unroll 4
        for (int p = 0; p < 32; ++p) {
            int ql = p * 8 + grp;
            int idx = sidx[ql];
            out[(qb0 + ql) * (D_FEAT / 4) + l32] = feat[idx * (D_FEAT / 4) + l32];
        }
    }
}

extern "C" void kernel_launch(void* const* d_in, const int* in_sizes, int n_in,
                              void* d_out, int out_size, void* d_ws, size_t ws_size,
                              hipStream_t stream) {
    const float* pts      = (const float*)d_in[0];   // (1,1024,32,3)
    const float* lidar    = (const float*)d_in[1];   // (1,8192,3)
    const float* features = (const float*)d_in[2];   // (1,8192,128)
    float* out = (float*)d_out;                      // (1,1024,32,128)

    char* ws = (char*)d_ws;
    unsigned long long* keys = (unsigned long long*)(ws + WS_KEYS);
    float* gpart  = (float*)(ws + WS_GPART);
    float4* qpack = (float4*)(ws + WS_QPK);
    float4* cpack = (float4*)(ws + WS_CPK);
    unsigned* cnt = (unsigned*)(ws + WS_CNT);

    k1_kernel<<<dim3(N_QBLK, NSEG), BLOCK, 0, stream>>>(
        pts, lidar, gpart, qpack, cpack, keys, cnt);
    k2_kernel<<<dim3(N_QBLK, NSEG), BLOCK, 0, stream>>>(
        pts, lidar, gpart, qpack, cpack, keys, cnt,
        (const float4*)features, (float4*)out);
}